// Round 7
// baseline (273.451 us; speedup 1.0000x reference)
//
#include <hip/hip_runtime.h>

// Problem constants (from reference)
#define C_IN   8
#define HH     32
#define WW     32
#define C_OUT  32
#define KK     4
#define SS     2
#define PP     1
#define HO     16
#define WO     16
#define IN_FEAT  8192   // C_IN*HH*WW
#define OUT_FEAT 8192   // C_OUT*HO*WO
#define WMAT_QUADS (OUT_FEAT * IN_FEAT / 4)   // 16,777,216 x 16B = 256 MiB

typedef float f32x4 __attribute__((ext_vector_type(4)));

// ---------------------------------------------------------------------------
// R6 post-mortem: measured kernel ~99us for a 268MB write (=2.7 TB/s eff),
// while the harness's own fillBufferAligned sustains 6.6 TB/s (83% peak) with
// a branch-free grid-stride dwordx4 loop -- write-allocate/NT was a red
// herring (cached fill hits 6.6 TB/s). So: make the bulk write EXACTLY
// fill-shaped, and peel the sparse tap logic into a tiny second kernel.
//
// Kernel 1 (zero_wmat): grid-stride f32x4 zero-fill of the 256 MiB Toeplitz
// matrix. Same instruction shape as rocclr's fill: ~41us @ 6.5 TB/s.
//
// Kernel 2 (scatter_taps): wmat is 99.5% zeros -- each row has <=128
// nonzeros: (ci,kh,kw) in 8x4x4, col = ci*1024 + (hs+kh)*32 + (ws+kw),
// value = weight[c_out,ci,kh,kw]. One wave per row scatters 2 scalar
// taps/lane into the zeroed matrix (stream order: fill first), and computes
// the interval bounds from the SAME weight loads + shuffle reduce
// (back-substitution == forward interval conv here; tighten is identity).
// ---------------------------------------------------------------------------

__global__ __launch_bounds__(256) void zero_wmat(f32x4* __restrict__ p) {
    const f32x4 z = (f32x4){0.f, 0.f, 0.f, 0.f};
    const int stride = gridDim.x * 256;
    for (int i = blockIdx.x * 256 + threadIdx.x; i < WMAT_QUADS; i += stride)
        p[i] = z;
}

__global__ __launch_bounds__(256) void scatter_taps(const float* __restrict__ bounds,
                                                    const float* __restrict__ weight,
                                                    const float* __restrict__ bias,
                                                    float* __restrict__ wmat,
                                                    float* __restrict__ out_bounds,
                                                    float* __restrict__ bias_bs) {
    const int gid  = blockIdx.x * 256 + threadIdx.x;
    const int row  = gid >> 6;                 // 0..8191 (wave-uniform)
    const int lane = threadIdx.x & 63;

    const int c_out = row >> 8;
    const int ho    = (row >> 4) & 15;
    const int wo    = row & 15;
    const int hs    = ho * SS - PP;            // window h start (may be -1)
    const int ws    = wo * SS - PP;            // window w start (may be -1)

    const float* __restrict__ wco  = weight + c_out * (C_IN * KK * KK);
    const float* __restrict__ lptr = bounds;             // bounds[0]
    const float* __restrict__ uptr = bounds + IN_FEAT;   // bounds[1]
    float* __restrict__ wrow = wmat + (size_t)row * IN_FEAT;

    float lo = 0.f, up = 0.f;
#pragma unroll
    for (int s = 0; s < 2; ++s) {
        const int t  = lane + 64 * s;          // tap 0..127 = (ci,kh,kw)
        const int ci = t >> 4;
        const int kh = (t >> 2) & 3;
        const int kw = t & 3;
        const int h  = hs + kh;
        const int w  = ws + kw;
        if ((unsigned)h < (unsigned)HH && (unsigned)w < (unsigned)WW) {
            const float wv  = wco[ci * (KK * KK) + kh * KK + kw];
            const int   col = ci * (HH * WW) + h * WW + w;
            wrow[col] = wv;                    // sparse tap into zeroed matrix
            const float lv = lptr[col];
            const float uv = uptr[col];
            const float wp = fmaxf(wv, 0.f);
            const float wm = fminf(wv, 0.f);
            lo = fmaf(wp, lv, fmaf(wm, uv, lo));
            up = fmaf(wp, uv, fmaf(wm, lv, up));
        }
    }
#pragma unroll
    for (int off = 32; off; off >>= 1) {
        lo += __shfl_down(lo, off, 64);
        up += __shfl_down(up, off, 64);
    }
    if (lane == 0) {
        const float b = bias[c_out];
        out_bounds[row]            = lo + b;   // lower  [32,16,16]
        out_bounds[OUT_FEAT + row] = up + b;   // upper
        bias_bs[row] = b;                      // repeat_interleave(bias, 256)
    }
}

extern "C" void kernel_launch(void* const* d_in, const int* in_sizes, int n_in,
                              void* d_out, int out_size, void* d_ws, size_t ws_size,
                              hipStream_t stream) {
    const float* bounds = (const float*)d_in[0];   // [2,8,32,32]
    const float* weight = (const float*)d_in[1];   // [32,8,4,4]
    const float* bias   = (const float*)d_in[2];   // [32]
    // d_in[3] = assignment (unused by forward)

    float* out     = (float*)d_out;
    float* wmat    = out + 2 * OUT_FEAT;                      // after out_bounds (16384)
    float* bias_bs = out + 2 * OUT_FEAT + (size_t)OUT_FEAT * IN_FEAT;

    // 1) fill-shaped zero of the 256 MiB matrix (proven 6.6 TB/s path shape)
    zero_wmat<<<2048, 256, 0, stream>>>(reinterpret_cast<f32x4*>(wmat));
    // 2) sparse taps + bounds; stream order guarantees taps land after zeros
    scatter_taps<<<2048, 256, 0, stream>>>(bounds, weight, bias, wmat, out, bias_bs);
}

// Round 8
// 262.569 us; speedup vs baseline: 1.0414x; 1.0414x over previous
//
#include <hip/hip_runtime.h>

// Problem constants (from reference)
#define C_IN   8
#define HH     32
#define WW     32
#define C_OUT  32
#define KK     4
#define SS     2
#define PP     1
#define HO     16
#define WO     16
#define IN_FEAT  8192   // C_IN*HH*WW
#define OUT_FEAT 8192   // C_OUT*HO*WO

// ---------------------------------------------------------------------------
// R8: decomposition round. R7 showed hand-written zero_wmat + scatter = 111.5us
// (worse than R6's fused 98.8us), but both our kernels are below the top-5
// counter cutoff so we can't see which one is slow. Replace the hand fill with
// hipMemsetAsync -- this dispatches the EXACT fillBufferAligned kernel the
// profile shows sustaining 6.6 TB/s (83% peak), and it appears as its own
// named dispatch in the trace. Single variable changed vs R7.
//
// wmat layout: row = c_out*256 + ho*16 + wo ; col = ci*1024 + h*32 + w
// nonzero iff h = 2*ho-1+kh, w = 2*wo-1+kw, kh,kw in [0,4), h,w in [0,32);
// value = weight[c_out, ci, kh, kw].  Matrix is 99.5% zeros: memset the
// 256 MiB, then scatter <=128 taps/row. Stream order guarantees taps land
// after zeros. Bounds (back-substitution == forward interval conv; tighten
// is identity) are computed in the scatter kernel from the same weight
// loads + wave shuffle-reduce.
// ---------------------------------------------------------------------------

__global__ __launch_bounds__(256) void scatter_taps(const float* __restrict__ bounds,
                                                    const float* __restrict__ weight,
                                                    const float* __restrict__ bias,
                                                    float* __restrict__ wmat,
                                                    float* __restrict__ out_bounds,
                                                    float* __restrict__ bias_bs) {
    const int gid  = blockIdx.x * 256 + threadIdx.x;
    const int row  = gid >> 6;                 // 0..8191 (wave-uniform)
    const int lane = threadIdx.x & 63;

    const int c_out = row >> 8;
    const int ho    = (row >> 4) & 15;
    const int wo    = row & 15;
    const int hs    = ho * SS - PP;            // window h start (may be -1)
    const int ws    = wo * SS - PP;            // window w start (may be -1)

    const float* __restrict__ wco  = weight + c_out * (C_IN * KK * KK);
    const float* __restrict__ lptr = bounds;             // bounds[0]
    const float* __restrict__ uptr = bounds + IN_FEAT;   // bounds[1]
    float* __restrict__ wrow = wmat + (size_t)row * IN_FEAT;

    float lo = 0.f, up = 0.f;
#pragma unroll
    for (int s = 0; s < 2; ++s) {
        const int t  = lane + 64 * s;          // tap 0..127 = (ci,kh,kw)
        const int ci = t >> 4;
        const int kh = (t >> 2) & 3;
        const int kw = t & 3;
        const int h  = hs + kh;
        const int w  = ws + kw;
        if ((unsigned)h < (unsigned)HH && (unsigned)w < (unsigned)WW) {
            const float wv  = wco[ci * (KK * KK) + kh * KK + kw];
            const int   col = ci * (HH * WW) + h * WW + w;
            wrow[col] = wv;                    // sparse tap into zeroed matrix
            const float lv = lptr[col];
            const float uv = uptr[col];
            const float wp = fmaxf(wv, 0.f);
            const float wm = fminf(wv, 0.f);
            lo = fmaf(wp, lv, fmaf(wm, uv, lo));
            up = fmaf(wp, uv, fmaf(wm, lv, up));
        }
    }
#pragma unroll
    for (int off = 32; off; off >>= 1) {
        lo += __shfl_down(lo, off, 64);
        up += __shfl_down(up, off, 64);
    }
    if (lane == 0) {
        const float b = bias[c_out];
        out_bounds[row]            = lo + b;   // lower  [32,16,16]
        out_bounds[OUT_FEAT + row] = up + b;   // upper
        bias_bs[row] = b;                      // repeat_interleave(bias, 256)
    }
}

extern "C" void kernel_launch(void* const* d_in, const int* in_sizes, int n_in,
                              void* d_out, int out_size, void* d_ws, size_t ws_size,
                              hipStream_t stream) {
    const float* bounds = (const float*)d_in[0];   // [2,8,32,32]
    const float* weight = (const float*)d_in[1];   // [32,8,4,4]
    const float* bias   = (const float*)d_in[2];   // [32]
    // d_in[3] = assignment (unused by forward)

    float* out     = (float*)d_out;
    float* wmat    = out + 2 * OUT_FEAT;                      // after out_bounds (16384)
    float* bias_bs = out + 2 * OUT_FEAT + (size_t)OUT_FEAT * IN_FEAT;

    // 1) zero the 256 MiB Toeplitz matrix via the driver's own fill kernel --
    //    the exact dispatch the profile shows at 6.6 TB/s. Async, capturable.
    hipMemsetAsync(wmat, 0, (size_t)OUT_FEAT * IN_FEAT * sizeof(float), stream);
    // 2) sparse taps + bounds; stream order guarantees taps land after zeros
    scatter_taps<<<2048, 256, 0, stream>>>(bounds, weight, bias, wmat, out, bias_bs);
}